// Round 10
// baseline (477.262 us; speedup 1.0000x reference)
//
#include <hip/hip_runtime.h>

// Problem constants (match reference setup_inputs)
constexpr int NV = 100000;   // vertices
constexpr int NE = 1600000;  // directed edges
constexpr int NB = 64;       // graphs
constexpr int HD = 128;      // hidden
constexpr int DM = 256;      // out dim
#define EPSLN 1e-5f

// CSR bucketing
constexpr int DPB   = 512;                      // dsts per bucket
constexpr int NBUCK = (NV + DPB - 1) / DPB;     // 196
constexpr int EPB   = 4096;                     // edges per block (bucket kernels)
constexpr int NEB   = (NE + EPB - 1) / EPB;     // 391

typedef short bf16x8 __attribute__((ext_vector_type(8)));
typedef float f32x4 __attribute__((ext_vector_type(4)));

__device__ inline unsigned short f2b(float f) {
    union { float f; unsigned u; } x; x.f = f;
    unsigned r = x.u + 0x7FFF + ((x.u >> 16) & 1);
    return (unsigned short)(r >> 16);
}
__device__ inline float b2f(unsigned short h) {
    union { unsigned u; float f; } x; x.u = (unsigned)h << 16;
    return x.f;
}

// ---------- bucket histogram: count edges per dst-bucket ----------
__global__ __launch_bounds__(256) void k_bhist(const int* __restrict__ ei,
                                               int* __restrict__ bcount) {
    __shared__ int h[NBUCK];
    int t = threadIdx.x;
    for (int i = t; i < NBUCK; i += 256) h[i] = 0;
    __syncthreads();
    int base = blockIdx.x * EPB;
    #pragma unroll
    for (int j = 0; j < EPB / 256; ++j) {
        int idx = base + j * 256 + t;
        if (idx < NE) atomicAdd(&h[ei[NE + idx] >> 9], 1);
    }
    __syncthreads();
    for (int i = t; i < NBUCK; i += 256) if (h[i]) atomicAdd(&bcount[i], h[i]);
}

__global__ void k_bscan(const int* __restrict__ bcount, int* __restrict__ bstart,
                        int* __restrict__ bcursor) {
    if (threadIdx.x == 0 && blockIdx.x == 0) {
        int run = 0;
        for (int i = 0; i < NBUCK; ++i) { bstart[i] = run; bcursor[i] = run; run += bcount[i]; }
        bstart[NBUCK] = run;
    }
}

// ---------- scatter edges into bucket regions (packed: (src<<9)|dstloc) ----------
__global__ __launch_bounds__(256) void k_bscatter(const int* __restrict__ ei,
                                                  int* __restrict__ bcursor,
                                                  int* __restrict__ ebuf) {
    __shared__ int h[NBUCK];
    __shared__ int lbase[NBUCK];
    int t = threadIdx.x;
    for (int i = t; i < NBUCK; i += 256) h[i] = 0;
    __syncthreads();
    int base = blockIdx.x * EPB;
    int s[16], d[16], rk[16];
    #pragma unroll
    for (int j = 0; j < 16; ++j) {
        int idx = base + j * 256 + t;
        if (idx < NE) {
            s[j] = ei[idx];
            d[j] = ei[NE + idx];
            rk[j] = atomicAdd(&h[d[j] >> 9], 1);
        } else d[j] = -1;
    }
    __syncthreads();
    for (int i = t; i < NBUCK; i += 256) {
        int c = h[i];
        if (c) lbase[i] = atomicAdd(&bcursor[i], c);
    }
    __syncthreads();
    #pragma unroll
    for (int j = 0; j < 16; ++j)
        if (d[j] >= 0) ebuf[lbase[d[j] >> 9] + rk[j]] = (s[j] << 9) | (d[j] & 511);
}

// ---------- fused per-bucket: histogram -> local scan -> deg/dinv/rowstart -> CSR fill ----------
__global__ __launch_bounds__(256) void k_bcsr(const int* __restrict__ ebuf,
                                              const int* __restrict__ bstart,
                                              int* __restrict__ degi,
                                              float* __restrict__ dinv,
                                              int* __restrict__ rowstart,
                                              int* __restrict__ csr) {
    __shared__ int h[DPB];
    __shared__ int sdata[256];
    int b = blockIdx.x, t = threadIdx.x, d0 = b * DPB;
    for (int i = t; i < DPB; i += 256) h[i] = 0;
    __syncthreads();
    int e0 = bstart[b], e1 = bstart[b + 1];
    for (int e = e0 + t; e < e1; e += 256) atomicAdd(&h[ebuf[e] & 511], 1);
    __syncthreads();
    int a = h[2 * t], c = h[2 * t + 1];
    sdata[t] = a + c;
    __syncthreads();
    for (int off = 1; off < 256; off <<= 1) {
        int v = sdata[t];
        int add = (t >= off) ? sdata[t - off] : 0;
        __syncthreads();
        sdata[t] = v + add;
        __syncthreads();
    }
    int excl = (t == 0) ? 0 : sdata[t - 1];
    int base = bstart[b];
    int v0 = d0 + 2 * t, v1 = v0 + 1;
    if (v0 < NV) { rowstart[v0] = base + excl;     degi[v0] = a; dinv[v0] = rsqrtf((float)a + 1.0f); }
    if (v1 < NV) { rowstart[v1] = base + excl + a; degi[v1] = c; dinv[v1] = rsqrtf((float)c + 1.0f); }
    // reuse h as cursors
    h[2 * t]     = base + excl;
    h[2 * t + 1] = base + excl + a;
    __syncthreads();
    for (int e = e0 + t; e < e1; e += 256) {
        int p = ebuf[e];
        int slot = atomicAdd(&h[p & 511], 1);
        csr[slot] = p >> 9;
    }
}

// ---------- layer-1 H from vertices; folds Wc = Win@W1, bc = bin@W1 per block ----------
__global__ __launch_bounds__(256) void k_h1(const float* __restrict__ verts,
                                            const float* __restrict__ Win,
                                            const float* __restrict__ bin,
                                            const float* __restrict__ W1,
                                            unsigned short* __restrict__ Hb) {
    __shared__ float Wc[3 * HD];
    __shared__ float bc[HD];
    int t = threadIdx.x;
    if (t < HD) {
        float w0 = 0.f, w1 = 0.f, w2 = 0.f, bv = 0.f;
        for (int k = 0; k < HD; ++k) {
            float w = W1[k * HD + t];
            w0 = fmaf(Win[k], w, w0);
            w1 = fmaf(Win[128 + k], w, w1);
            w2 = fmaf(Win[256 + k], w, w2);
            bv = fmaf(bin[k], w, bv);
        }
        Wc[t] = w0; Wc[128 + t] = w1; Wc[256 + t] = w2; bc[t] = bv;
    }
    __syncthreads();
    for (int idx = blockIdx.x * 256 + t; idx < NV * HD; idx += gridDim.x * 256) {
        int v = idx >> 7, c = idx & 127;
        float a = verts[v * 3 + 0], b = verts[v * 3 + 1], d = verts[v * 3 + 2];
        Hb[idx] = f2b(bc[c] + a * Wc[c] + b * Wc[128 + c] + d * Wc[256 + c]);
    }
}

// ---------- W2,W3 [k][n] f32 -> Wt [l][n][k] bf16 ----------
__global__ void k_wt2(const float* __restrict__ W2, const float* __restrict__ W3,
                      unsigned short* __restrict__ Wt) {
    int idx = blockIdx.x * 256 + threadIdx.x;
    if (idx >= 2 * HD * HD) return;
    int l = idx >> 14, r = idx & 16383;
    const float* W = (l == 0) ? W2 : W3;
    int n = r >> 7, k = r & 127;
    Wt[idx - r + n * HD + k] = f2b(W[k * HD + n]);
}

// ---------- H = X @ W  via MFMA bf16: 4 waves/block, 64 rows/block ----------
__global__ __launch_bounds__(256) void k_gemm_mfma(const unsigned short* __restrict__ Xb,
                                                   const unsigned short* __restrict__ Wt,
                                                   unsigned short* __restrict__ Hb) {
    int wave = threadIdx.x >> 6;
    int lane = threadIdx.x & 63;
    int r = lane & 15;
    int g = lane >> 4;                     // 0..3
    int row0 = blockIdx.x * 64 + wave * 16;
    int arow = row0 + r;
    bool valid = arow < NV;

    bf16x8 afrag[4];
    const unsigned short* xp = Xb + (size_t)arow * HD + g * 8;
    #pragma unroll
    for (int ks = 0; ks < 4; ++ks) {
        if (valid) afrag[ks] = *(const bf16x8*)(xp + ks * 32);
        else       afrag[ks] = bf16x8{0, 0, 0, 0, 0, 0, 0, 0};
    }

    #pragma unroll
    for (int nt = 0; nt < 8; ++nt) {
        f32x4 acc = {0.f, 0.f, 0.f, 0.f};
        const unsigned short* wp = Wt + (size_t)(nt * 16 + r) * HD + g * 8;
        #pragma unroll
        for (int ks = 0; ks < 4; ++ks) {
            bf16x8 bfrag = *(const bf16x8*)(wp + ks * 32);
            acc = __builtin_amdgcn_mfma_f32_16x16x32_bf16(afrag[ks], bfrag, acc, 0, 0, 0);
        }
        #pragma unroll
        for (int j = 0; j < 4; ++j) {
            int row = row0 + g * 4 + j;   // C/D: col = lane&15, row = (lane>>4)*4 + reg
            if (row < NV)
                Hb[(size_t)row * HD + nt * 16 + r] = f2b(acc[j]);
        }
    }
}

// ---------- aggregate (column-split): one wave per dst, 8 groups x 8 lanes ----------
// Each dispatch gathers only 64 of the 128 columns (128 B/row) -> halved L2
// working set (12.8 MB), higher hit rate on the gather.
__global__ __launch_bounds__(256) void k_agg(const unsigned short* __restrict__ H,
                                             const float* __restrict__ dinv,
                                             const int* __restrict__ rowstart,
                                             const int* __restrict__ degi,
                                             const int* __restrict__ csr_src,
                                             const float* __restrict__ bias,
                                             unsigned short* __restrict__ Xo,
                                             int colbase) {
    int gtid = blockIdx.x * 256 + threadIdx.x;
    int v = gtid >> 6;
    if (v >= NV) return;
    int lane = threadIdx.x & 63;
    int g = lane >> 3;        // group 0..7: edges g, g+8, g+16, ...
    int l3 = lane & 7;        // col sub: cols colbase + l3*8 .. +7
    const unsigned short* Hc = H + colbase;
    float di = dinv[v];
    int rs = rowstart[v], len = degi[v];
    float a[8];
    if (g == 0) {
        float sc = di * di;
        bf16x8 hv = *(const bf16x8*)(Hc + (size_t)v * HD + l3 * 8);
        #pragma unroll
        for (int jj = 0; jj < 8; ++jj) a[jj] = b2f((unsigned short)hv[jj]) * sc;
    } else {
        #pragma unroll
        for (int jj = 0; jj < 8; ++jj) a[jj] = 0.f;
    }
    int cnt = (len - g + 7) >> 3;   // edges this group handles
    int idx = rs + g;
    int j = 0;
    for (; j + 1 < cnt; j += 2) {
        int s0 = csr_src[idx], s1 = csr_src[idx + 8];
        idx += 16;
        float w0 = dinv[s0] * di, w1 = dinv[s1] * di;
        bf16x8 h0 = *(const bf16x8*)(Hc + (size_t)s0 * HD + l3 * 8);
        bf16x8 h1 = *(const bf16x8*)(Hc + (size_t)s1 * HD + l3 * 8);
        #pragma unroll
        for (int jj = 0; jj < 8; ++jj) {
            a[jj] = fmaf(b2f((unsigned short)h0[jj]), w0, a[jj]);
            a[jj] = fmaf(b2f((unsigned short)h1[jj]), w1, a[jj]);
        }
    }
    if (j < cnt) {
        int s0 = csr_src[idx];
        float w0 = dinv[s0] * di;
        bf16x8 h0 = *(const bf16x8*)(Hc + (size_t)s0 * HD + l3 * 8);
        #pragma unroll
        for (int jj = 0; jj < 8; ++jj)
            a[jj] = fmaf(b2f((unsigned short)h0[jj]), w0, a[jj]);
    }
    // reduce across the 8 groups (lanes l3, l3+8, ..., l3+56)
    #pragma unroll
    for (int jj = 0; jj < 8; ++jj) {
        a[jj] += __shfl_xor(a[jj], 8);
        a[jj] += __shfl_xor(a[jj], 16);
        a[jj] += __shfl_xor(a[jj], 32);
    }
    if (g == 0) {
        bf16x8 ov;
        #pragma unroll
        for (int jj = 0; jj < 8; ++jj)
            ov[jj] = (short)f2b(fmaxf(a[jj] + bias[colbase + l3 * 8 + jj], 0.f));
        *(bf16x8*)(Xo + (size_t)v * HD + colbase + l3 * 8) = ov;
    }
}

// ---------- mean pool: 2048 blocks x 256 thr, register run-length accumulate ----------
__global__ __launch_bounds__(256) void k_pool(const unsigned short* __restrict__ X,
                                              const int* __restrict__ batch,
                                              float* __restrict__ pool,
                                              int* __restrict__ cnt) {
    constexpr int NCHUNK = 2048;
    constexpr int CHUNK = (NV + NCHUNK - 1) / NCHUNK;  // 49
    int c = threadIdx.x & 127;
    int r = threadIdx.x >> 7;
    int v0 = blockIdx.x * CHUNK;
    if (v0 >= NV) return;
    int vend = min(v0 + CHUNK, NV);
    int cur = -1;
    float sum = 0.f;
    for (int v = v0 + r; v < vend; v += 2) {
        int bb = batch[v];
        if (bb != cur) {
            if (cur >= 0) atomicAdd(&pool[cur * HD + c], sum);
            cur = bb; sum = 0.f;
        }
        sum += b2f(X[(size_t)v * HD + c]);
    }
    if (cur >= 0) atomicAdd(&pool[cur * HD + c], sum);
    if (threadIdx.x == 0) {
        int prev = batch[v0]; int c0 = 0;
        for (int v = v0; v < vend; ++v) {
            int bb = batch[v];
            if (bb != prev) { atomicAdd(&cnt[prev], c0); prev = bb; c0 = 0; }
            ++c0;
        }
        atomicAdd(&cnt[prev], c0);
    }
}

// ---------- final linear + layernorm, one block per graph ----------
__global__ __launch_bounds__(256) void k_out(const float* __restrict__ pool,
                                             const int* __restrict__ cnt,
                                             const float* __restrict__ Wout,
                                             const float* __restrict__ bout,
                                             const float* __restrict__ gamma,
                                             const float* __restrict__ beta,
                                             float* __restrict__ out) {
    __shared__ float ps[HD];
    __shared__ float red[DM];
    int g = blockIdx.x, t = threadIdx.x;
    if (t < HD) {
        float cn = fmaxf((float)cnt[g], 1.0f);
        ps[t] = pool[g * HD + t] / cn;
    }
    __syncthreads();
    float acc = bout[t];
    #pragma unroll 8
    for (int k = 0; k < HD; ++k) acc = fmaf(ps[k], Wout[k * DM + t], acc);
    red[t] = acc; __syncthreads();
    for (int s2 = 128; s2 > 0; s2 >>= 1) {
        if (t < s2) red[t] += red[t + s2];
        __syncthreads();
    }
    float mu = red[0] * (1.0f / DM);
    __syncthreads();
    float d = acc - mu;
    red[t] = d * d; __syncthreads();
    for (int s2 = 128; s2 > 0; s2 >>= 1) {
        if (t < s2) red[t] += red[t + s2];
        __syncthreads();
    }
    float var = red[0] * (1.0f / DM);
    out[g * DM + t] = d * rsqrtf(var + EPSLN) * gamma[t] + beta[t];
}

extern "C" void kernel_launch(void* const* d_in, const int* in_sizes, int n_in,
                              void* d_out, int out_size, void* d_ws, size_t ws_size,
                              hipStream_t stream) {
    const float* verts = (const float*)d_in[0];
    const int*   ei    = (const int*)d_in[1];
    const int*   batch = (const int*)d_in[2];
    const float* Win   = (const float*)d_in[3];
    const float* bin   = (const float*)d_in[4];
    const float* W1    = (const float*)d_in[5];
    const float* b1    = (const float*)d_in[6];
    const float* W2    = (const float*)d_in[7];
    const float* b2    = (const float*)d_in[8];
    const float* W3    = (const float*)d_in[9];
    const float* b3    = (const float*)d_in[10];
    const float* Wout  = (const float*)d_in[11];
    const float* bout  = (const float*)d_in[12];
    const float* gamma = (const float*)d_in[13];
    const float* beta  = (const float*)d_in[14];
    float* out = (float*)d_out;

    char* wp = (char*)d_ws;
    auto alloc = [&](size_t bytes) -> char* {
        char* p = wp;
        wp += (bytes + 255) & ~(size_t)255;
        return p;
    };
    unsigned short* bufA = (unsigned short*)alloc((size_t)NV * HD * 2);
    unsigned short* bufB = (unsigned short*)alloc((size_t)NV * HD * 2);
    unsigned short* Wt   = (unsigned short*)alloc((size_t)2 * HD * HD * 2);
    int*   degi     = (int*)alloc((size_t)NV * 4);
    float* dinv     = (float*)alloc((size_t)NV * 4);
    int*   rowstart = (int*)alloc((size_t)NV * 4);
    int*   csr      = (int*)alloc((size_t)NE * 4);
    int*   ebuf     = (int*)alloc((size_t)NE * 4);
    int*   bcount   = (int*)alloc((size_t)NBUCK * 4);
    int*   bstart   = (int*)alloc((size_t)(NBUCK + 1) * 4);
    int*   bcursor  = (int*)alloc((size_t)NBUCK * 4);
    float* pool     = (float*)alloc((size_t)NB * HD * 4);
    int*   cnt      = (int*)alloc((size_t)NB * 4);

    hipMemsetAsync(bcount, 0, (size_t)NBUCK * 4, stream);
    hipMemsetAsync(pool,   0, (size_t)NB * HD * 4, stream);
    hipMemsetAsync(cnt,    0, (size_t)NB * 4, stream);

    // CSR build (bucketed, L2-local)
    k_bhist<<<NEB, 256, 0, stream>>>(ei, bcount);
    k_bscan<<<1, 64, 0, stream>>>(bcount, bstart, bcursor);
    k_bscatter<<<NEB, 256, 0, stream>>>(ei, bcursor, ebuf);
    k_bcsr<<<NBUCK, 256, 0, stream>>>(ebuf, bstart, degi, dinv, rowstart, csr);

    // weights prep + layer-1 H (input linear folded)
    k_wt2<<<(2 * HD * HD + 255) / 256, 256, 0, stream>>>(W2, W3, Wt);
    k_h1<<<1024, 256, 0, stream>>>(verts, Win, bin, W1, bufA);

    int aggrid = (int)(((size_t)NV * 64 + 255) / 256);
    // layer 1
    k_agg<<<aggrid, 256, 0, stream>>>(bufA, dinv, rowstart, degi, csr, b1, bufB, 0);
    k_agg<<<aggrid, 256, 0, stream>>>(bufA, dinv, rowstart, degi, csr, b1, bufB, 64);
    k_gemm_mfma<<<(NV + 63) / 64, 256, 0, stream>>>(bufB, Wt, bufA);
    // layer 2
    k_agg<<<aggrid, 256, 0, stream>>>(bufA, dinv, rowstart, degi, csr, b2, bufB, 0);
    k_agg<<<aggrid, 256, 0, stream>>>(bufA, dinv, rowstart, degi, csr, b2, bufB, 64);
    k_gemm_mfma<<<(NV + 63) / 64, 256, 0, stream>>>(bufB, Wt + (size_t)HD * HD, bufA);
    // layer 3
    k_agg<<<aggrid, 256, 0, stream>>>(bufA, dinv, rowstart, degi, csr, b3, bufB, 0);
    k_agg<<<aggrid, 256, 0, stream>>>(bufA, dinv, rowstart, degi, csr, b3, bufB, 64);

    k_pool<<<2048, 256, 0, stream>>>(bufB, batch, pool, cnt);
    k_out<<<NB, 256, 0, stream>>>(pool, cnt, Wout, bout, gamma, beta, out);
}

// Round 11
// 375.468 us; speedup vs baseline: 1.2711x; 1.2711x over previous
//
#include <hip/hip_runtime.h>

// Problem constants (match reference setup_inputs)
constexpr int NV = 100000;   // vertices
constexpr int NE = 1600000;  // directed edges
constexpr int NB = 64;       // graphs
constexpr int HD = 128;      // hidden
constexpr int DM = 256;      // out dim
#define EPSLN 1e-5f

// CSR bucketing (fixed-capacity bucket regions; no global scan needed)
constexpr int DPB   = 512;                      // dsts per bucket
constexpr int NBUCK = (NV + DPB - 1) / DPB;     // 196
constexpr int BCAP  = 16384;                    // edges capacity per bucket (mean 8163, 6 sigma ~8700)
constexpr int EPB   = 4096;                     // edges per block (scatter kernel)
constexpr int NEB   = (NE + EPB - 1) / EPB;     // 391

typedef short bf16x8 __attribute__((ext_vector_type(8)));
typedef float f32x4 __attribute__((ext_vector_type(4)));

__device__ inline unsigned short f2b(float f) {
    union { float f; unsigned u; } x; x.f = f;
    unsigned r = x.u + 0x7FFF + ((x.u >> 16) & 1);
    return (unsigned short)(r >> 16);
}
__device__ inline float b2f(unsigned short h) {
    union { unsigned u; float f; } x; x.u = (unsigned)h << 16;
    return x.f;
}

// ---------- scatter edges into fixed-capacity bucket regions ----------
__global__ __launch_bounds__(256) void k_bscatter(const int* __restrict__ ei,
                                                  int* __restrict__ bcursor,
                                                  int* __restrict__ ebuf) {
    __shared__ int h[NBUCK];
    __shared__ int lbase[NBUCK];
    int t = threadIdx.x;
    for (int i = t; i < NBUCK; i += 256) h[i] = 0;
    __syncthreads();
    int base = blockIdx.x * EPB;
    int s[16], d[16], rk[16];
    #pragma unroll
    for (int j = 0; j < 16; ++j) {
        int idx = base + j * 256 + t;
        if (idx < NE) {
            s[j] = ei[idx];
            d[j] = ei[NE + idx];
            rk[j] = atomicAdd(&h[d[j] >> 9], 1);
        } else d[j] = -1;
    }
    __syncthreads();
    for (int i = t; i < NBUCK; i += 256) {
        int c = h[i];
        if (c) lbase[i] = atomicAdd(&bcursor[i], c);
    }
    __syncthreads();
    #pragma unroll
    for (int j = 0; j < 16; ++j)
        if (d[j] >= 0) {
            int b = d[j] >> 9;
            ebuf[(b << 14) + lbase[b] + rk[j]] = (s[j] << 9) | (d[j] & 511);
        }
}

// ---------- fused per-bucket: histogram -> local scan -> deg/dinv/rowstart -> CSR fill ----------
__global__ __launch_bounds__(256) void k_bcsr(const int* __restrict__ ebuf,
                                              const int* __restrict__ bcursor,
                                              int* __restrict__ degi,
                                              float* __restrict__ dinv,
                                              int* __restrict__ rowstart,
                                              int* __restrict__ csr) {
    __shared__ int h[DPB];
    __shared__ int sdata[256];
    int b = blockIdx.x, t = threadIdx.x, d0 = b * DPB;
    for (int i = t; i < DPB; i += 256) h[i] = 0;
    __syncthreads();
    int e0 = b << 14;
    int e1 = e0 + bcursor[b];
    for (int e = e0 + t; e < e1; e += 256) atomicAdd(&h[ebuf[e] & 511], 1);
    __syncthreads();
    int a = h[2 * t], c = h[2 * t + 1];
    sdata[t] = a + c;
    __syncthreads();
    for (int off = 1; off < 256; off <<= 1) {
        int v = sdata[t];
        int add = (t >= off) ? sdata[t - off] : 0;
        __syncthreads();
        sdata[t] = v + add;
        __syncthreads();
    }
    int excl = (t == 0) ? 0 : sdata[t - 1];
    int base = e0;   // csr shares the bucket-strided layout
    int v0 = d0 + 2 * t, v1 = v0 + 1;
    if (v0 < NV) { rowstart[v0] = base + excl;     degi[v0] = a; dinv[v0] = rsqrtf((float)a + 1.0f); }
    if (v1 < NV) { rowstart[v1] = base + excl + a; degi[v1] = c; dinv[v1] = rsqrtf((float)c + 1.0f); }
    // reuse h as cursors
    h[2 * t]     = base + excl;
    h[2 * t + 1] = base + excl + a;
    __syncthreads();
    for (int e = e0 + t; e < e1; e += 256) {
        int p = ebuf[e];
        int slot = atomicAdd(&h[p & 511], 1);
        csr[slot] = p >> 9;
    }
}

// ---------- layer-1 H from vertices; folds Wc = Win@W1, bc = bin@W1 per block ----------
__global__ __launch_bounds__(256) void k_h1(const float* __restrict__ verts,
                                            const float* __restrict__ Win,
                                            const float* __restrict__ bin,
                                            const float* __restrict__ W1,
                                            unsigned short* __restrict__ Hb) {
    __shared__ float Wc[3 * HD];
    __shared__ float bc[HD];
    int t = threadIdx.x;
    if (t < HD) {
        float w0 = 0.f, w1 = 0.f, w2 = 0.f, bv = 0.f;
        for (int k = 0; k < HD; ++k) {
            float w = W1[k * HD + t];
            w0 = fmaf(Win[k], w, w0);
            w1 = fmaf(Win[128 + k], w, w1);
            w2 = fmaf(Win[256 + k], w, w2);
            bv = fmaf(bin[k], w, bv);
        }
        Wc[t] = w0; Wc[128 + t] = w1; Wc[256 + t] = w2; bc[t] = bv;
    }
    __syncthreads();
    for (int idx = blockIdx.x * 256 + t; idx < NV * HD; idx += gridDim.x * 256) {
        int v = idx >> 7, c = idx & 127;
        float a = verts[v * 3 + 0], b = verts[v * 3 + 1], d = verts[v * 3 + 2];
        Hb[idx] = f2b(bc[c] + a * Wc[c] + b * Wc[128 + c] + d * Wc[256 + c]);
    }
}

// ---------- W2,W3 [k][n] f32 -> Wt [l][n][k] bf16 ----------
__global__ void k_wt2(const float* __restrict__ W2, const float* __restrict__ W3,
                      unsigned short* __restrict__ Wt) {
    int idx = blockIdx.x * 256 + threadIdx.x;
    if (idx >= 2 * HD * HD) return;
    int l = idx >> 14, r = idx & 16383;
    const float* W = (l == 0) ? W2 : W3;
    int n = r >> 7, k = r & 127;
    Wt[idx - r + n * HD + k] = f2b(W[k * HD + n]);
}

// ---------- H = X @ W via MFMA; LDS-repack epilogue for coalesced 16B stores ----------
__global__ __launch_bounds__(256) void k_gemm_mfma(const unsigned short* __restrict__ Xb,
                                                   const unsigned short* __restrict__ Wt,
                                                   unsigned short* __restrict__ Hb) {
    __shared__ __align__(16) unsigned short hs[4][16][136];
    int wave = threadIdx.x >> 6;
    int lane = threadIdx.x & 63;
    int r = lane & 15;
    int g = lane >> 4;                     // 0..3
    int row0 = blockIdx.x * 64 + wave * 16;
    int arow = row0 + r;
    bool valid = arow < NV;

    bf16x8 afrag[4];
    const unsigned short* xp = Xb + (size_t)arow * HD + g * 8;
    #pragma unroll
    for (int ks = 0; ks < 4; ++ks) {
        if (valid) afrag[ks] = *(const bf16x8*)(xp + ks * 32);
        else       afrag[ks] = bf16x8{0, 0, 0, 0, 0, 0, 0, 0};
    }

    #pragma unroll
    for (int nt = 0; nt < 8; ++nt) {
        f32x4 acc = {0.f, 0.f, 0.f, 0.f};
        const unsigned short* wp = Wt + (size_t)(nt * 16 + r) * HD + g * 8;
        #pragma unroll
        for (int ks = 0; ks < 4; ++ks) {
            bf16x8 bfrag = *(const bf16x8*)(wp + ks * 32);
            acc = __builtin_amdgcn_mfma_f32_16x16x32_bf16(afrag[ks], bfrag, acc, 0, 0, 0);
        }
        // C/D: col = lane&15 (=r), row = g*4 + j  -> stash in LDS, repack below
        #pragma unroll
        for (int j = 0; j < 4; ++j)
            hs[wave][g * 4 + j][nt * 16 + r] = f2b(acc[j]);
    }
    __syncthreads();
    // repack: each lane stores 4 x 16B contiguous chunks
    int row = lane >> 2;                 // 0..15
    int grow = row0 - wave * 16 + (threadIdx.x >> 2 & 0xFFFF);  // placeholder avoided; compute directly
    grow = blockIdx.x * 64 + wave * 16 + row;
    #pragma unroll
    for (int k = 0; k < 4; ++k) {
        int c = (lane & 3) + k * 4;      // chunk 0..15 (8 shorts each)
        bf16x8 val = *(const bf16x8*)&hs[wave][row][c * 8];
        if (grow < NV)
            *(bf16x8*)(Hb + (size_t)grow * HD + c * 8) = val;
    }
}

// ---------- aggregate: one wave per dst, quarter-waves over edges, bf16x8 rows ----------
__global__ __launch_bounds__(256) void k_agg(const unsigned short* __restrict__ H,
                                             const float* __restrict__ dinv,
                                             const int* __restrict__ rowstart,
                                             const int* __restrict__ degi,
                                             const int* __restrict__ csr_src,
                                             const float* __restrict__ bias,
                                             unsigned short* __restrict__ Xo) {
    int gtid = blockIdx.x * 256 + threadIdx.x;
    int v = gtid >> 6;
    if (v >= NV) return;
    int lane = threadIdx.x & 63;
    int q = lane >> 4;        // quarter 0..3: edges q, q+4, ...
    int l4 = lane & 15;       // col group: cols l4*8 .. l4*8+7
    float di = dinv[v];
    int rs = rowstart[v], len = degi[v];
    float a[8];
    if (q == 0) {
        float sc = di * di;
        bf16x8 hv = *(const bf16x8*)(H + (size_t)v * HD + l4 * 8);
        #pragma unroll
        for (int jj = 0; jj < 8; ++jj) a[jj] = b2f((unsigned short)hv[jj]) * sc;
    } else {
        #pragma unroll
        for (int jj = 0; jj < 8; ++jj) a[jj] = 0.f;
    }
    int cnt = (len - q + 3) >> 2;   // edges this quarter handles
    int idx = rs + q;
    int j = 0;
    for (; j + 1 < cnt; j += 2) {
        int s0 = csr_src[idx], s1 = csr_src[idx + 4];
        idx += 8;
        float w0 = dinv[s0] * di, w1 = dinv[s1] * di;
        bf16x8 h0 = *(const bf16x8*)(H + (size_t)s0 * HD + l4 * 8);
        bf16x8 h1 = *(const bf16x8*)(H + (size_t)s1 * HD + l4 * 8);
        #pragma unroll
        for (int jj = 0; jj < 8; ++jj) {
            a[jj] = fmaf(b2f((unsigned short)h0[jj]), w0, a[jj]);
            a[jj] = fmaf(b2f((unsigned short)h1[jj]), w1, a[jj]);
        }
    }
    if (j < cnt) {
        int s0 = csr_src[idx];
        float w0 = dinv[s0] * di;
        bf16x8 h0 = *(const bf16x8*)(H + (size_t)s0 * HD + l4 * 8);
        #pragma unroll
        for (int jj = 0; jj < 8; ++jj)
            a[jj] = fmaf(b2f((unsigned short)h0[jj]), w0, a[jj]);
    }
    // reduce across quarters (lanes l4, l4+16, l4+32, l4+48)
    #pragma unroll
    for (int jj = 0; jj < 8; ++jj) {
        a[jj] += __shfl_xor(a[jj], 16);
        a[jj] += __shfl_xor(a[jj], 32);
    }
    if (q == 0) {
        bf16x8 ov;
        #pragma unroll
        for (int jj = 0; jj < 8; ++jj)
            ov[jj] = (short)f2b(fmaxf(a[jj] + bias[l4 * 8 + jj], 0.f));
        *(bf16x8*)(Xo + (size_t)v * HD + l4 * 8) = ov;
    }
}

// ---------- mean pool: 2048 blocks x 256 thr, register run-length accumulate ----------
__global__ __launch_bounds__(256) void k_pool(const unsigned short* __restrict__ X,
                                              const int* __restrict__ batch,
                                              float* __restrict__ pool,
                                              int* __restrict__ cnt) {
    constexpr int NCHUNK = 2048;
    constexpr int CHUNK = (NV + NCHUNK - 1) / NCHUNK;  // 49
    int c = threadIdx.x & 127;
    int r = threadIdx.x >> 7;
    int v0 = blockIdx.x * CHUNK;
    if (v0 >= NV) return;
    int vend = min(v0 + CHUNK, NV);
    int cur = -1;
    float sum = 0.f;
    for (int v = v0 + r; v < vend; v += 2) {
        int bb = batch[v];
        if (bb != cur) {
            if (cur >= 0) atomicAdd(&pool[cur * HD + c], sum);
            cur = bb; sum = 0.f;
        }
        sum += b2f(X[(size_t)v * HD + c]);
    }
    if (cur >= 0) atomicAdd(&pool[cur * HD + c], sum);
    if (threadIdx.x == 0) {
        int prev = batch[v0]; int c0 = 0;
        for (int v = v0; v < vend; ++v) {
            int bb = batch[v];
            if (bb != prev) { atomicAdd(&cnt[prev], c0); prev = bb; c0 = 0; }
            ++c0;
        }
        atomicAdd(&cnt[prev], c0);
    }
}

// ---------- final linear + layernorm, one block per graph ----------
__global__ __launch_bounds__(256) void k_out(const float* __restrict__ pool,
                                             const int* __restrict__ cnt,
                                             const float* __restrict__ Wout,
                                             const float* __restrict__ bout,
                                             const float* __restrict__ gamma,
                                             const float* __restrict__ beta,
                                             float* __restrict__ out) {
    __shared__ float ps[HD];
    __shared__ float red[DM];
    int g = blockIdx.x, t = threadIdx.x;
    if (t < HD) {
        float cn = fmaxf((float)cnt[g], 1.0f);
        ps[t] = pool[g * HD + t] / cn;
    }
    __syncthreads();
    float acc = bout[t];
    #pragma unroll 8
    for (int k = 0; k < HD; ++k) acc = fmaf(ps[k], Wout[k * DM + t], acc);
    red[t] = acc; __syncthreads();
    for (int s2 = 128; s2 > 0; s2 >>= 1) {
        if (t < s2) red[t] += red[t + s2];
        __syncthreads();
    }
    float mu = red[0] * (1.0f / DM);
    __syncthreads();
    float d = acc - mu;
    red[t] = d * d; __syncthreads();
    for (int s2 = 128; s2 > 0; s2 >>= 1) {
        if (t < s2) red[t] += red[t + s2];
        __syncthreads();
    }
    float var = red[0] * (1.0f / DM);
    out[g * DM + t] = d * rsqrtf(var + EPSLN) * gamma[t] + beta[t];
}

extern "C" void kernel_launch(void* const* d_in, const int* in_sizes, int n_in,
                              void* d_out, int out_size, void* d_ws, size_t ws_size,
                              hipStream_t stream) {
    const float* verts = (const float*)d_in[0];
    const int*   ei    = (const int*)d_in[1];
    const int*   batch = (const int*)d_in[2];
    const float* Win   = (const float*)d_in[3];
    const float* bin   = (const float*)d_in[4];
    const float* W1    = (const float*)d_in[5];
    const float* b1    = (const float*)d_in[6];
    const float* W2    = (const float*)d_in[7];
    const float* b2    = (const float*)d_in[8];
    const float* W3    = (const float*)d_in[9];
    const float* b3    = (const float*)d_in[10];
    const float* Wout  = (const float*)d_in[11];
    const float* bout  = (const float*)d_in[12];
    const float* gamma = (const float*)d_in[13];
    const float* beta  = (const float*)d_in[14];
    float* out = (float*)d_out;

    char* wp = (char*)d_ws;
    auto alloc = [&](size_t bytes) -> char* {
        char* p = wp;
        wp += (bytes + 255) & ~(size_t)255;
        return p;
    };
    unsigned short* bufA = (unsigned short*)alloc((size_t)NV * HD * 2);
    unsigned short* bufB = (unsigned short*)alloc((size_t)NV * HD * 2);
    unsigned short* Wt   = (unsigned short*)alloc((size_t)2 * HD * HD * 2);
    int*   degi     = (int*)alloc((size_t)NV * 4);
    float* dinv     = (float*)alloc((size_t)NV * 4);
    int*   rowstart = (int*)alloc((size_t)NV * 4);
    int*   csr      = (int*)alloc((size_t)NBUCK * BCAP * 4);
    int*   ebuf     = (int*)alloc((size_t)NBUCK * BCAP * 4);
    int*   bcursor  = (int*)alloc((size_t)NBUCK * 4);
    float* pool     = (float*)alloc((size_t)NB * HD * 4);
    int*   cnt      = (int*)alloc((size_t)NB * 4);

    hipMemsetAsync(bcursor, 0, (size_t)NBUCK * 4, stream);
    hipMemsetAsync(pool,    0, (size_t)NB * HD * 4, stream);
    hipMemsetAsync(cnt,     0, (size_t)NB * 4, stream);

    // CSR build (fixed-capacity buckets, L2-local)
    k_bscatter<<<NEB, 256, 0, stream>>>(ei, bcursor, ebuf);
    k_bcsr<<<NBUCK, 256, 0, stream>>>(ebuf, bcursor, degi, dinv, rowstart, csr);

    // weights prep + layer-1 H (input linear folded)
    k_wt2<<<(2 * HD * HD + 255) / 256, 256, 0, stream>>>(W2, W3, Wt);
    k_h1<<<1024, 256, 0, stream>>>(verts, Win, bin, W1, bufA);

    int aggrid = (int)(((size_t)NV * 64 + 255) / 256);
    // layer 1
    k_agg<<<aggrid, 256, 0, stream>>>(bufA, dinv, rowstart, degi, csr, b1, bufB);
    k_gemm_mfma<<<(NV + 63) / 64, 256, 0, stream>>>(bufB, Wt, bufA);
    // layer 2
    k_agg<<<aggrid, 256, 0, stream>>>(bufA, dinv, rowstart, degi, csr, b2, bufB);
    k_gemm_mfma<<<(NV + 63) / 64, 256, 0, stream>>>(bufB, Wt + (size_t)HD * HD, bufA);
    // layer 3
    k_agg<<<aggrid, 256, 0, stream>>>(bufA, dinv, rowstart, degi, csr, b3, bufB);

    k_pool<<<2048, 256, 0, stream>>>(bufB, batch, pool, cnt);
    k_out<<<NB, 256, 0, stream>>>(pool, cnt, Wout, bout, gamma, beta, out);
}

// Round 12
// 345.476 us; speedup vs baseline: 1.3815x; 1.0868x over previous
//
#include <hip/hip_runtime.h>

// Problem constants (match reference setup_inputs)
constexpr int NV = 100000;   // vertices
constexpr int NE = 1600000;  // directed edges
constexpr int NB = 64;       // graphs
constexpr int HD = 128;      // hidden
constexpr int DM = 256;      // out dim
#define EPSLN 1e-5f

// CSR bucketing (fixed-capacity bucket regions; no global scan needed)
constexpr int DPB   = 512;                      // dsts per bucket
constexpr int NBUCK = (NV + DPB - 1) / DPB;     // 196
constexpr int BCAP  = 16384;                    // per-bucket capacity (mean 8163, >>6 sigma)
constexpr int EPB   = 4096;                     // edges per block (scatter kernel)
constexpr int NEB   = (NE + EPB - 1) / EPB;     // 391

typedef short bf16x8 __attribute__((ext_vector_type(8)));
typedef float f32x4 __attribute__((ext_vector_type(4)));

__device__ inline unsigned short f2b(float f) {
    union { float f; unsigned u; } x; x.f = f;
    unsigned r = x.u + 0x7FFF + ((x.u >> 16) & 1);
    return (unsigned short)(r >> 16);
}
__device__ inline float b2f(unsigned short h) {
    union { unsigned u; float f; } x; x.u = (unsigned)h << 16;
    return x.f;
}

// ---------- scatter edges into fixed-capacity bucket regions ----------
__global__ __launch_bounds__(256) void k_bscatter(const int* __restrict__ ei,
                                                  int* __restrict__ bcursor,
                                                  int* __restrict__ ebuf) {
    __shared__ int h[NBUCK];
    __shared__ int lbase[NBUCK];
    int t = threadIdx.x;
    for (int i = t; i < NBUCK; i += 256) h[i] = 0;
    __syncthreads();
    int base = blockIdx.x * EPB;
    int s[16], d[16], rk[16];
    #pragma unroll
    for (int j = 0; j < 16; ++j) {
        int idx = base + j * 256 + t;
        if (idx < NE) {
            s[j] = ei[idx];
            d[j] = ei[NE + idx];
            rk[j] = atomicAdd(&h[d[j] >> 9], 1);
        } else d[j] = -1;
    }
    __syncthreads();
    for (int i = t; i < NBUCK; i += 256) {
        int c = h[i];
        if (c) lbase[i] = atomicAdd(&bcursor[i], c);
    }
    __syncthreads();
    #pragma unroll
    for (int j = 0; j < 16; ++j)
        if (d[j] >= 0) {
            int b = d[j] >> 9;
            ebuf[(b << 14) + lbase[b] + rk[j]] = (s[j] << 9) | (d[j] & 511);
        }
}

// ---------- fused per-bucket: histogram -> local scan -> deg/dinv/rowstart -> CSR fill ----------
__global__ __launch_bounds__(256) void k_bcsr(const int* __restrict__ ebuf,
                                              const int* __restrict__ bcursor,
                                              int* __restrict__ degi,
                                              float* __restrict__ dinv,
                                              int* __restrict__ rowstart,
                                              int* __restrict__ csr) {
    __shared__ int h[DPB];
    __shared__ int sdata[256];
    int b = blockIdx.x, t = threadIdx.x, d0 = b * DPB;
    for (int i = t; i < DPB; i += 256) h[i] = 0;
    __syncthreads();
    int e0 = b << 14;
    int e1 = e0 + bcursor[b];
    for (int e = e0 + t; e < e1; e += 256) atomicAdd(&h[ebuf[e] & 511], 1);
    __syncthreads();
    int a = h[2 * t], c = h[2 * t + 1];
    sdata[t] = a + c;
    __syncthreads();
    for (int off = 1; off < 256; off <<= 1) {
        int v = sdata[t];
        int add = (t >= off) ? sdata[t - off] : 0;
        __syncthreads();
        sdata[t] = v + add;
        __syncthreads();
    }
    int excl = (t == 0) ? 0 : sdata[t - 1];
    int base = e0;   // csr shares the bucket-strided layout
    int v0 = d0 + 2 * t, v1 = v0 + 1;
    if (v0 < NV) { rowstart[v0] = base + excl;     degi[v0] = a; dinv[v0] = rsqrtf((float)a + 1.0f); }
    if (v1 < NV) { rowstart[v1] = base + excl + a; degi[v1] = c; dinv[v1] = rsqrtf((float)c + 1.0f); }
    // reuse h as cursors
    h[2 * t]     = base + excl;
    h[2 * t + 1] = base + excl + a;
    __syncthreads();
    for (int e = e0 + t; e < e1; e += 256) {
        int p = ebuf[e];
        int slot = atomicAdd(&h[p & 511], 1);
        csr[slot] = p >> 9;
    }
}

// ---------- prep: blocks <1024 compute layer-1 H (input linear folded);
//            blocks >=1024 transpose W2,W3 to bf16 [n][k] ----------
__global__ __launch_bounds__(256) void k_prep(const float* __restrict__ verts,
                                              const float* __restrict__ Win,
                                              const float* __restrict__ bin,
                                              const float* __restrict__ W1,
                                              const float* __restrict__ W2,
                                              const float* __restrict__ W3,
                                              unsigned short* __restrict__ Hb,
                                              unsigned short* __restrict__ Wt) {
    int t = threadIdx.x;
    if (blockIdx.x >= 1024) {
        int idx = (blockIdx.x - 1024) * 256 + t;   // 0..32767
        if (idx < 2 * HD * HD) {
            int l = idx >> 14, r = idx & 16383;
            const float* W = (l == 0) ? W2 : W3;
            int n = r >> 7, k = r & 127;
            Wt[(l << 14) + n * HD + k] = f2b(W[k * HD + n]);
        }
        return;
    }
    __shared__ float Wc[3 * HD];
    __shared__ float bc[HD];
    if (t < HD) {
        float w0 = 0.f, w1 = 0.f, w2 = 0.f, bv = 0.f;
        for (int k = 0; k < HD; ++k) {
            float w = W1[k * HD + t];
            w0 = fmaf(Win[k], w, w0);
            w1 = fmaf(Win[128 + k], w, w1);
            w2 = fmaf(Win[256 + k], w, w2);
            bv = fmaf(bin[k], w, bv);
        }
        Wc[t] = w0; Wc[128 + t] = w1; Wc[256 + t] = w2; bc[t] = bv;
    }
    __syncthreads();
    for (int idx = blockIdx.x * 256 + t; idx < NV * HD; idx += 1024 * 256) {
        int v = idx >> 7, c = idx & 127;
        float a = verts[v * 3 + 0], b = verts[v * 3 + 1], d = verts[v * 3 + 2];
        Hb[idx] = f2b(bc[c] + a * Wc[c] + b * Wc[128 + c] + d * Wc[256 + c]);
    }
}

// ---------- H = X @ W via MFMA; Wt staged in padded LDS; coalesced epilogue ----------
__global__ __launch_bounds__(256) void k_gemm_mfma(const unsigned short* __restrict__ Xb,
                                                   const unsigned short* __restrict__ Wt,
                                                   unsigned short* __restrict__ Hb) {
    __shared__ __align__(16) unsigned short Ws[128 * 132];   // padded rows: bank-spread
    __shared__ __align__(16) unsigned short hs[4][16][136];  // per-wave repack buffer
    int t = threadIdx.x;
    {   // stage Wt -> LDS: thread loads 128 shorts (row t>>1, half (t&1)*64)
        int row = t >> 1;
        int half = (t & 1) << 6;
        const unsigned short* src = Wt + row * HD + half;
        unsigned short* dst = &Ws[row * 132 + half];
        #pragma unroll
        for (int i = 0; i < 8; ++i)
            *(bf16x8*)(dst + i * 8) = *(const bf16x8*)(src + i * 8);
    }
    int wave = t >> 6;
    int lane = t & 63;
    int r = lane & 15;
    int g = lane >> 4;                     // 0..3
    int row0 = blockIdx.x * 64 + wave * 16;
    int arow = row0 + r;
    bool valid = arow < NV;

    bf16x8 afrag[4];
    const unsigned short* xp = Xb + (size_t)arow * HD + g * 8;
    #pragma unroll
    for (int ks = 0; ks < 4; ++ks) {
        if (valid) afrag[ks] = *(const bf16x8*)(xp + ks * 32);
        else       afrag[ks] = bf16x8{0, 0, 0, 0, 0, 0, 0, 0};
    }
    __syncthreads();

    #pragma unroll
    for (int nt = 0; nt < 8; ++nt) {
        f32x4 acc = {0.f, 0.f, 0.f, 0.f};
        #pragma unroll
        for (int ks = 0; ks < 4; ++ks) {
            bf16x8 bfrag = *(const bf16x8*)&Ws[(nt * 16 + r) * 132 + g * 8 + ks * 32];
            acc = __builtin_amdgcn_mfma_f32_16x16x32_bf16(afrag[ks], bfrag, acc, 0, 0, 0);
        }
        // C/D: col = lane&15 (=r), row = g*4 + j -> stash in per-wave LDS tile
        #pragma unroll
        for (int j = 0; j < 4; ++j)
            hs[wave][g * 4 + j][nt * 16 + r] = f2b(acc[j]);
    }
    // within-wave repack (hs[wave] is private to this wave; no barrier)
    int row = lane >> 2;
    int grow = row0 + row;
    #pragma unroll
    for (int k = 0; k < 4; ++k) {
        int c = (lane & 3) + k * 4;      // chunk 0..15 (8 shorts each)
        bf16x8 val = *(const bf16x8*)&hs[wave][row][c * 8];
        if (grow < NV)
            *(bf16x8*)(Hb + (size_t)grow * HD + c * 8) = val;
    }
}

// ---------- aggregate: one wave per dst, quarter-waves over edges, bf16x8 rows ----------
__global__ __launch_bounds__(256) void k_agg(const unsigned short* __restrict__ H,
                                             const float* __restrict__ dinv,
                                             const int* __restrict__ rowstart,
                                             const int* __restrict__ degi,
                                             const int* __restrict__ csr_src,
                                             const float* __restrict__ bias,
                                             unsigned short* __restrict__ Xo) {
    int gtid = blockIdx.x * 256 + threadIdx.x;
    int v = gtid >> 6;
    if (v >= NV) return;
    int lane = threadIdx.x & 63;
    int q = lane >> 4;        // quarter 0..3: edges q, q+4, ...
    int l4 = lane & 15;       // col group: cols l4*8 .. l4*8+7
    float di = dinv[v];
    int rs = rowstart[v], len = degi[v];
    float a[8];
    if (q == 0) {
        float sc = di * di;
        bf16x8 hv = *(const bf16x8*)(H + (size_t)v * HD + l4 * 8);
        #pragma unroll
        for (int jj = 0; jj < 8; ++jj) a[jj] = b2f((unsigned short)hv[jj]) * sc;
    } else {
        #pragma unroll
        for (int jj = 0; jj < 8; ++jj) a[jj] = 0.f;
    }
    int cnt = (len - q + 3) >> 2;   // edges this quarter handles
    int idx = rs + q;
    int j = 0;
    for (; j + 1 < cnt; j += 2) {
        int s0 = csr_src[idx], s1 = csr_src[idx + 4];
        idx += 8;
        float w0 = dinv[s0] * di, w1 = dinv[s1] * di;
        bf16x8 h0 = *(const bf16x8*)(H + (size_t)s0 * HD + l4 * 8);
        bf16x8 h1 = *(const bf16x8*)(H + (size_t)s1 * HD + l4 * 8);
        #pragma unroll
        for (int jj = 0; jj < 8; ++jj) {
            a[jj] = fmaf(b2f((unsigned short)h0[jj]), w0, a[jj]);
            a[jj] = fmaf(b2f((unsigned short)h1[jj]), w1, a[jj]);
        }
    }
    if (j < cnt) {
        int s0 = csr_src[idx];
        float w0 = dinv[s0] * di;
        bf16x8 h0 = *(const bf16x8*)(H + (size_t)s0 * HD + l4 * 8);
        #pragma unroll
        for (int jj = 0; jj < 8; ++jj)
            a[jj] = fmaf(b2f((unsigned short)h0[jj]), w0, a[jj]);
    }
    // reduce across quarters (lanes l4, l4+16, l4+32, l4+48)
    #pragma unroll
    for (int jj = 0; jj < 8; ++jj) {
        a[jj] += __shfl_xor(a[jj], 16);
        a[jj] += __shfl_xor(a[jj], 32);
    }
    if (q == 0) {
        bf16x8 ov;
        #pragma unroll
        for (int jj = 0; jj < 8; ++jj)
            ov[jj] = (short)f2b(fmaxf(a[jj] + bias[l4 * 8 + jj], 0.f));
        *(bf16x8*)(Xo + (size_t)v * HD + l4 * 8) = ov;
    }
}

// ---------- mean pool: vectorized bf16x8 loads; <=2 graphs per 49-row chunk ----------
__global__ __launch_bounds__(256) void k_pool(const unsigned short* __restrict__ X,
                                              const int* __restrict__ batch,
                                              float* __restrict__ pool,
                                              int* __restrict__ cnt) {
    constexpr int CHUNK = (NV + 2047) / 2048;  // 49
    __shared__ float lp[2][HD];
    __shared__ int binfo[2];
    int t = threadIdx.x;
    int v0 = blockIdx.x * CHUNK;
    if (v0 >= NV) return;
    int vend = min(v0 + CHUNK, NV);
    if (t < 2 * HD) ((float*)lp)[t] = 0.f;
    if (t == 0) { binfo[0] = batch[v0]; binfo[1] = batch[vend - 1]; }
    __syncthreads();
    int b0 = binfo[0], b1 = binfo[1];
    int cg = t & 15;      // col group (8 cols)
    int ro = t >> 4;      // 0..15 row offset
    if (b1 - b0 <= 1) {
        float a0[8] = {}, a1[8] = {};
        for (int v = v0 + ro; v < vend; v += 16) {
            bf16x8 x = *(const bf16x8*)(X + (size_t)v * HD + cg * 8);
            if (batch[v] == b0) {
                #pragma unroll
                for (int jj = 0; jj < 8; ++jj) a0[jj] += b2f((unsigned short)x[jj]);
            } else {
                #pragma unroll
                for (int jj = 0; jj < 8; ++jj) a1[jj] += b2f((unsigned short)x[jj]);
            }
        }
        #pragma unroll
        for (int jj = 0; jj < 8; ++jj) {
            atomicAdd(&lp[0][cg * 8 + jj], a0[jj]);
            if (b1 != b0) atomicAdd(&lp[1][cg * 8 + jj], a1[jj]);
        }
        __syncthreads();
        int slot = t >> 7, col = t & 127;
        if (slot == 0 || b1 != b0)
            atomicAdd(&pool[(slot ? b1 : b0) * HD + col], lp[slot][col]);
    } else {
        // rare (>2 graphs in a 49-row chunk): direct global flush
        float a[8] = {};
        int cur = -1;
        for (int v = v0 + ro; v < vend; v += 16) {
            int bb = batch[v];
            if (bb != cur) {
                if (cur >= 0) {
                    #pragma unroll
                    for (int jj = 0; jj < 8; ++jj) {
                        atomicAdd(&pool[cur * HD + cg * 8 + jj], a[jj]);
                        a[jj] = 0.f;
                    }
                }
                cur = bb;
            }
            bf16x8 x = *(const bf16x8*)(X + (size_t)v * HD + cg * 8);
            #pragma unroll
            for (int jj = 0; jj < 8; ++jj) a[jj] += b2f((unsigned short)x[jj]);
        }
        if (cur >= 0) {
            #pragma unroll
            for (int jj = 0; jj < 8; ++jj)
                atomicAdd(&pool[cur * HD + cg * 8 + jj], a[jj]);
        }
    }
    if (t == 0) {
        int prev = batch[v0], c0 = 0;
        for (int v = v0; v < vend; ++v) {
            int bb = batch[v];
            if (bb != prev) { atomicAdd(&cnt[prev], c0); prev = bb; c0 = 0; }
            ++c0;
        }
        atomicAdd(&cnt[prev], c0);
    }
}

// ---------- final linear + layernorm, one block per graph ----------
__global__ __launch_bounds__(256) void k_out(const float* __restrict__ pool,
                                             const int* __restrict__ cnt,
                                             const float* __restrict__ Wout,
                                             const float* __restrict__ bout,
                                             const float* __restrict__ gamma,
                                             const float* __restrict__ beta,
                                             float* __restrict__ out) {
    __shared__ float ps[HD];
    __shared__ float red[DM];
    int g = blockIdx.x, t = threadIdx.x;
    if (t < HD) {
        float cn = fmaxf((float)cnt[g], 1.0f);
        ps[t] = pool[g * HD + t] / cn;
    }
    __syncthreads();
    float acc = bout[t];
    #pragma unroll 8
    for (int k = 0; k < HD; ++k) acc = fmaf(ps[k], Wout[k * DM + t], acc);
    red[t] = acc; __syncthreads();
    for (int s2 = 128; s2 > 0; s2 >>= 1) {
        if (t < s2) red[t] += red[t + s2];
        __syncthreads();
    }
    float mu = red[0] * (1.0f / DM);
    __syncthreads();
    float d = acc - mu;
    red[t] = d * d; __syncthreads();
    for (int s2 = 128; s2 > 0; s2 >>= 1) {
        if (t < s2) red[t] += red[t + s2];
        __syncthreads();
    }
    float var = red[0] * (1.0f / DM);
    out[g * DM + t] = d * rsqrtf(var + EPSLN) * gamma[t] + beta[t];
}

extern "C" void kernel_launch(void* const* d_in, const int* in_sizes, int n_in,
                              void* d_out, int out_size, void* d_ws, size_t ws_size,
                              hipStream_t stream) {
    const float* verts = (const float*)d_in[0];
    const int*   ei    = (const int*)d_in[1];
    const int*   batch = (const int*)d_in[2];
    const float* Win   = (const float*)d_in[3];
    const float* bin   = (const float*)d_in[4];
    const float* W1    = (const float*)d_in[5];
    const float* b1    = (const float*)d_in[6];
    const float* W2    = (const float*)d_in[7];
    const float* b2    = (const float*)d_in[8];
    const float* W3    = (const float*)d_in[9];
    const float* b3    = (const float*)d_in[10];
    const float* Wout  = (const float*)d_in[11];
    const float* bout  = (const float*)d_in[12];
    const float* gamma = (const float*)d_in[13];
    const float* beta  = (const float*)d_in[14];
    float* out = (float*)d_out;

    char* wp = (char*)d_ws;
    auto alloc = [&](size_t bytes) -> char* {
        char* p = wp;
        wp += (bytes + 255) & ~(size_t)255;
        return p;
    };
    unsigned short* bufA = (unsigned short*)alloc((size_t)NV * HD * 2);
    unsigned short* bufB = (unsigned short*)alloc((size_t)NV * HD * 2);
    unsigned short* Wt   = (unsigned short*)alloc((size_t)2 * HD * HD * 2);
    int*   degi     = (int*)alloc((size_t)NV * 4);
    float* dinv     = (float*)alloc((size_t)NV * 4);
    int*   rowstart = (int*)alloc((size_t)NV * 4);
    int*   csr      = (int*)alloc((size_t)NBUCK * BCAP * 4);
    int*   ebuf     = (int*)alloc((size_t)NBUCK * BCAP * 4);
    // contiguous zero region: bcursor | pool | cnt -> one memset
    char*  zblock   = alloc(1024 + (size_t)NB * HD * 4 + 1024);
    int*   bcursor  = (int*)zblock;
    float* pool     = (float*)(zblock + 1024);
    int*   cnt      = (int*)(zblock + 1024 + (size_t)NB * HD * 4);

    hipMemsetAsync(zblock, 0, 1024 + (size_t)NB * HD * 4 + 1024, stream);

    // CSR build (fixed-capacity buckets, L2-local)
    k_bscatter<<<NEB, 256, 0, stream>>>(ei, bcursor, ebuf);
    k_bcsr<<<NBUCK, 256, 0, stream>>>(ebuf, bcursor, degi, dinv, rowstart, csr);

    // prep: layer-1 H (input linear folded) + W2/W3 transpose, one kernel
    k_prep<<<1152, 256, 0, stream>>>(verts, Win, bin, W1, W2, W3, bufA, Wt);

    int aggrid = (int)(((size_t)NV * 64 + 255) / 256);
    // layer 1
    k_agg<<<aggrid, 256, 0, stream>>>(bufA, dinv, rowstart, degi, csr, b1, bufB);
    k_gemm_mfma<<<(NV + 63) / 64, 256, 0, stream>>>(bufB, Wt, bufA);
    // layer 2
    k_agg<<<aggrid, 256, 0, stream>>>(bufA, dinv, rowstart, degi, csr, b2, bufB);
    k_gemm_mfma<<<(NV + 63) / 64, 256, 0, stream>>>(bufB, Wt + (size_t)HD * HD, bufA);
    // layer 3
    k_agg<<<aggrid, 256, 0, stream>>>(bufA, dinv, rowstart, degi, csr, b3, bufB);

    k_pool<<<2048, 256, 0, stream>>>(bufB, batch, pool, cnt);
    k_out<<<NB, 256, 0, stream>>>(pool, cnt, Wout, bout, gamma, beta, out);
}

// Round 13
// 339.540 us; speedup vs baseline: 1.4056x; 1.0175x over previous
//
#include <hip/hip_runtime.h>

// Problem constants (match reference setup_inputs)
constexpr int NV = 100000;   // vertices
constexpr int NE = 1600000;  // directed edges
constexpr int NB = 64;       // graphs
constexpr int HD = 128;      // hidden
constexpr int DM = 256;      // out dim
#define EPSLN 1e-5f

// CSR bucketing (fixed-capacity bucket regions; no global scan needed)
constexpr int DPB   = 512;                      // dsts per bucket
constexpr int NBUCK = (NV + DPB - 1) / DPB;     // 196
constexpr int BCAP  = 16384;                    // per-bucket capacity (mean 8163, >>6 sigma)
constexpr int EPB2  = 2048;                     // edges per block (scatter part of k_init)
constexpr int NEB2  = (NE + EPB2 - 1) / EPB2;   // 782
constexpr int H1B   = 1024;                     // h1 blocks
constexpr int WTB   = 128;                      // wt-transpose blocks
constexpr int LCAP  = 12288;                    // LDS-staged edges per bucket (mean+45sigma)

typedef short bf16x8 __attribute__((ext_vector_type(8)));
typedef float f32x4 __attribute__((ext_vector_type(4)));

__device__ inline unsigned short f2b(float f) {
    union { float f; unsigned u; } x; x.f = f;
    unsigned r = x.u + 0x7FFF + ((x.u >> 16) & 1);
    return (unsigned short)(r >> 16);
}
__device__ inline float b2f(unsigned short h) {
    union { unsigned u; float f; } x; x.u = (unsigned)h << 16;
    return x.f;
}

// ---------- fused init: [0,NEB2) edge scatter | [NEB2,+H1B) layer-1 H | rest: W transpose ----------
__global__ __launch_bounds__(256) void k_init(const float* __restrict__ verts,
                                              const float* __restrict__ Win,
                                              const float* __restrict__ bin,
                                              const float* __restrict__ W1,
                                              const float* __restrict__ W2,
                                              const float* __restrict__ W3,
                                              const int* __restrict__ ei,
                                              int* __restrict__ bcursor,
                                              int* __restrict__ ebuf,
                                              unsigned short* __restrict__ Hb,
                                              unsigned short* __restrict__ Wt) {
    int t = threadIdx.x;
    int bid = blockIdx.x;
    if (bid < NEB2) {
        // ---- scatter edges into fixed-capacity bucket regions ----
        __shared__ int h[NBUCK];
        __shared__ int lbase[NBUCK];
        for (int i = t; i < NBUCK; i += 256) h[i] = 0;
        __syncthreads();
        int base = bid * EPB2;
        int s[8], d[8], rk[8];
        #pragma unroll
        for (int j = 0; j < 8; ++j) {
            int idx = base + j * 256 + t;
            if (idx < NE) {
                s[j] = ei[idx];
                d[j] = ei[NE + idx];
                rk[j] = atomicAdd(&h[d[j] >> 9], 1);
            } else d[j] = -1;
        }
        __syncthreads();
        for (int i = t; i < NBUCK; i += 256) {
            int c = h[i];
            if (c) lbase[i] = atomicAdd(&bcursor[i], c);
        }
        __syncthreads();
        #pragma unroll
        for (int j = 0; j < 8; ++j)
            if (d[j] >= 0) {
                int b = d[j] >> 9;
                ebuf[(b << 14) + lbase[b] + rk[j]] = (s[j] << 9) | (d[j] & 511);
            }
        return;
    }
    if (bid < NEB2 + H1B) {
        // ---- layer-1 H from vertices; folds Wc = Win@W1, bc = bin@W1 ----
        __shared__ float Wc[3 * HD];
        __shared__ float bc[HD];
        if (t < HD) {
            float w0 = 0.f, w1 = 0.f, w2 = 0.f, bv = 0.f;
            for (int k = 0; k < HD; ++k) {
                float w = W1[k * HD + t];
                w0 = fmaf(Win[k], w, w0);
                w1 = fmaf(Win[128 + k], w, w1);
                w2 = fmaf(Win[256 + k], w, w2);
                bv = fmaf(bin[k], w, bv);
            }
            Wc[t] = w0; Wc[128 + t] = w1; Wc[256 + t] = w2; bc[t] = bv;
        }
        __syncthreads();
        for (int idx = (bid - NEB2) * 256 + t; idx < NV * HD; idx += H1B * 256) {
            int v = idx >> 7, c = idx & 127;
            float a = verts[v * 3 + 0], b = verts[v * 3 + 1], d = verts[v * 3 + 2];
            Hb[idx] = f2b(bc[c] + a * Wc[c] + b * Wc[128 + c] + d * Wc[256 + c]);
        }
        return;
    }
    // ---- W2,W3 [k][n] f32 -> Wt [l][n][k] bf16 ----
    int idx = (bid - NEB2 - H1B) * 256 + t;   // 0..32767
    if (idx < 2 * HD * HD) {
        int l = idx >> 14, r = idx & 16383;
        const float* W = (l == 0) ? W2 : W3;
        int n = r >> 7, k = r & 127;
        Wt[(l << 14) + n * HD + k] = f2b(W[k * HD + n]);
    }
}

// ---------- per-bucket CSR: LDS-staged edges, 512 thr, hist -> scan -> fill ----------
__global__ __launch_bounds__(512) void k_bcsr(const int* __restrict__ ebuf,
                                              const int* __restrict__ bcursor,
                                              int* __restrict__ degi,
                                              float* __restrict__ dinv,
                                              int* __restrict__ rowstart,
                                              int* __restrict__ csr) {
    __shared__ int els[LCAP];
    __shared__ int h[DPB];
    __shared__ int sdata[DPB];
    int b = blockIdx.x, t = threadIdx.x, d0 = b * DPB;
    if (t < DPB) h[t] = 0;
    __syncthreads();
    int e0 = b << 14;
    int n = bcursor[b];
    for (int i = t; i < n; i += 512) {
        int p = ebuf[e0 + i];
        if (i < LCAP) els[i] = p;
        atomicAdd(&h[p & 511], 1);
    }
    __syncthreads();
    int a = h[t];
    sdata[t] = a;
    __syncthreads();
    for (int off = 1; off < 512; off <<= 1) {
        int v = sdata[t];
        int add = (t >= off) ? sdata[t - off] : 0;
        __syncthreads();
        sdata[t] = v + add;
        __syncthreads();
    }
    int excl = (t == 0) ? 0 : sdata[t - 1];
    int v0 = d0 + t;
    if (v0 < NV) {
        rowstart[v0] = e0 + excl;
        degi[v0] = a;
        dinv[v0] = rsqrtf((float)a + 1.0f);
    }
    h[t] = e0 + excl;
    __syncthreads();
    for (int i = t; i < n; i += 512) {
        int p = (i < LCAP) ? els[i] : ebuf[e0 + i];
        int slot = atomicAdd(&h[p & 511], 1);
        csr[slot] = p >> 9;
    }
}

// ---------- H = X @ W via MFMA; Wt staged in padded LDS; coalesced epilogue ----------
__global__ __launch_bounds__(256) void k_gemm_mfma(const unsigned short* __restrict__ Xb,
                                                   const unsigned short* __restrict__ Wt,
                                                   unsigned short* __restrict__ Hb) {
    __shared__ __align__(16) unsigned short Ws[128 * 132];   // padded rows: bank-spread
    __shared__ __align__(16) unsigned short hs[4][16][136];  // per-wave repack buffer
    int t = threadIdx.x;
    {   // stage Wt -> LDS: thread loads 128 shorts (row t>>1, half (t&1)*64)
        int row = t >> 1;
        int half = (t & 1) << 6;
        const unsigned short* src = Wt + row * HD + half;
        unsigned short* dst = &Ws[row * 132 + half];
        #pragma unroll
        for (int i = 0; i < 8; ++i)
            *(bf16x8*)(dst + i * 8) = *(const bf16x8*)(src + i * 8);
    }
    int wave = t >> 6;
    int lane = t & 63;
    int r = lane & 15;
    int g = lane >> 4;                     // 0..3
    int row0 = blockIdx.x * 64 + wave * 16;
    int arow = row0 + r;
    bool valid = arow < NV;

    bf16x8 afrag[4];
    const unsigned short* xp = Xb + (size_t)arow * HD + g * 8;
    #pragma unroll
    for (int ks = 0; ks < 4; ++ks) {
        if (valid) afrag[ks] = *(const bf16x8*)(xp + ks * 32);
        else       afrag[ks] = bf16x8{0, 0, 0, 0, 0, 0, 0, 0};
    }
    __syncthreads();

    #pragma unroll
    for (int nt = 0; nt < 8; ++nt) {
        f32x4 acc = {0.f, 0.f, 0.f, 0.f};
        #pragma unroll
        for (int ks = 0; ks < 4; ++ks) {
            bf16x8 bfrag = *(const bf16x8*)&Ws[(nt * 16 + r) * 132 + g * 8 + ks * 32];
            acc = __builtin_amdgcn_mfma_f32_16x16x32_bf16(afrag[ks], bfrag, acc, 0, 0, 0);
        }
        // C/D: col = lane&15 (=r), row = g*4 + j -> stash in per-wave LDS tile
        #pragma unroll
        for (int j = 0; j < 4; ++j)
            hs[wave][g * 4 + j][nt * 16 + r] = f2b(acc[j]);
    }
    // within-wave repack (hs[wave] is private to this wave; no barrier)
    int row = lane >> 2;
    int grow = row0 + row;
    #pragma unroll
    for (int k = 0; k < 4; ++k) {
        int c = (lane & 3) + k * 4;      // chunk 0..15 (8 shorts each)
        bf16x8 val = *(const bf16x8*)&hs[wave][row][c * 8];
        if (grow < NV)
            *(bf16x8*)(Hb + (size_t)grow * HD + c * 8) = val;
    }
}

// ---------- aggregate: one wave per dst, quarter-waves over edges, bf16x8 rows ----------
__global__ __launch_bounds__(256) void k_agg(const unsigned short* __restrict__ H,
                                             const float* __restrict__ dinv,
                                             const int* __restrict__ rowstart,
                                             const int* __restrict__ degi,
                                             const int* __restrict__ csr_src,
                                             const float* __restrict__ bias,
                                             unsigned short* __restrict__ Xo) {
    int gtid = blockIdx.x * 256 + threadIdx.x;
    int v = gtid >> 6;
    if (v >= NV) return;
    int lane = threadIdx.x & 63;
    int q = lane >> 4;        // quarter 0..3: edges q, q+4, ...
    int l4 = lane & 15;       // col group: cols l4*8 .. l4*8+7
    float di = dinv[v];
    int rs = rowstart[v], len = degi[v];
    float a[8];
    if (q == 0) {
        float sc = di * di;
        bf16x8 hv = *(const bf16x8*)(H + (size_t)v * HD + l4 * 8);
        #pragma unroll
        for (int jj = 0; jj < 8; ++jj) a[jj] = b2f((unsigned short)hv[jj]) * sc;
    } else {
        #pragma unroll
        for (int jj = 0; jj < 8; ++jj) a[jj] = 0.f;
    }
    int cnt = (len - q + 3) >> 2;   // edges this quarter handles
    int idx = rs + q;
    int j = 0;
    for (; j + 1 < cnt; j += 2) {
        int s0 = csr_src[idx], s1 = csr_src[idx + 4];
        idx += 8;
        float w0 = dinv[s0] * di, w1 = dinv[s1] * di;
        bf16x8 h0 = *(const bf16x8*)(H + (size_t)s0 * HD + l4 * 8);
        bf16x8 h1 = *(const bf16x8*)(H + (size_t)s1 * HD + l4 * 8);
        #pragma unroll
        for (int jj = 0; jj < 8; ++jj) {
            a[jj] = fmaf(b2f((unsigned short)h0[jj]), w0, a[jj]);
            a[jj] = fmaf(b2f((unsigned short)h1[jj]), w1, a[jj]);
        }
    }
    if (j < cnt) {
        int s0 = csr_src[idx];
        float w0 = dinv[s0] * di;
        bf16x8 h0 = *(const bf16x8*)(H + (size_t)s0 * HD + l4 * 8);
        #pragma unroll
        for (int jj = 0; jj < 8; ++jj)
            a[jj] = fmaf(b2f((unsigned short)h0[jj]), w0, a[jj]);
    }
    // reduce across quarters (lanes l4, l4+16, l4+32, l4+48)
    #pragma unroll
    for (int jj = 0; jj < 8; ++jj) {
        a[jj] += __shfl_xor(a[jj], 16);
        a[jj] += __shfl_xor(a[jj], 32);
    }
    if (q == 0) {
        bf16x8 ov;
        #pragma unroll
        for (int jj = 0; jj < 8; ++jj)
            ov[jj] = (short)f2b(fmaxf(a[jj] + bias[l4 * 8 + jj], 0.f));
        *(bf16x8*)(Xo + (size_t)v * HD + l4 * 8) = ov;
    }
}

// ---------- mean pool: vectorized bf16x8 loads; <=2 graphs per 49-row chunk ----------
__global__ __launch_bounds__(256) void k_pool(const unsigned short* __restrict__ X,
                                              const int* __restrict__ batch,
                                              float* __restrict__ pool,
                                              int* __restrict__ cnt) {
    constexpr int CHUNK = (NV + 2047) / 2048;  // 49
    __shared__ float lp[2][HD];
    __shared__ int binfo[2];
    int t = threadIdx.x;
    int v0 = blockIdx.x * CHUNK;
    if (v0 >= NV) return;
    int vend = min(v0 + CHUNK, NV);
    if (t < 2 * HD) ((float*)lp)[t] = 0.f;
    if (t == 0) { binfo[0] = batch[v0]; binfo[1] = batch[vend - 1]; }
    __syncthreads();
    int b0 = binfo[0], b1 = binfo[1];
    int cg = t & 15;      // col group (8 cols)
    int ro = t >> 4;      // 0..15 row offset
    if (b1 - b0 <= 1) {
        float a0[8] = {}, a1[8] = {};
        for (int v = v0 + ro; v < vend; v += 16) {
            bf16x8 x = *(const bf16x8*)(X + (size_t)v * HD + cg * 8);
            if (batch[v] == b0) {
                #pragma unroll
                for (int jj = 0; jj < 8; ++jj) a0[jj] += b2f((unsigned short)x[jj]);
            } else {
                #pragma unroll
                for (int jj = 0; jj < 8; ++jj) a1[jj] += b2f((unsigned short)x[jj]);
            }
        }
        #pragma unroll
        for (int jj = 0; jj < 8; ++jj) {
            atomicAdd(&lp[0][cg * 8 + jj], a0[jj]);
            if (b1 != b0) atomicAdd(&lp[1][cg * 8 + jj], a1[jj]);
        }
        __syncthreads();
        int slot = t >> 7, col = t & 127;
        if (slot == 0 || b1 != b0)
            atomicAdd(&pool[(slot ? b1 : b0) * HD + col], lp[slot][col]);
    } else {
        float a[8] = {};
        int cur = -1;
        for (int v = v0 + ro; v < vend; v += 16) {
            int bb = batch[v];
            if (bb != cur) {
                if (cur >= 0) {
                    #pragma unroll
                    for (int jj = 0; jj < 8; ++jj) {
                        atomicAdd(&pool[cur * HD + cg * 8 + jj], a[jj]);
                        a[jj] = 0.f;
                    }
                }
                cur = bb;
            }
            bf16x8 x = *(const bf16x8*)(X + (size_t)v * HD + cg * 8);
            #pragma unroll
            for (int jj = 0; jj < 8; ++jj) a[jj] += b2f((unsigned short)x[jj]);
        }
        if (cur >= 0) {
            #pragma unroll
            for (int jj = 0; jj < 8; ++jj)
                atomicAdd(&pool[cur * HD + cg * 8 + jj], a[jj]);
        }
    }
    if (t == 0) {
        int prev = batch[v0], c0 = 0;
        for (int v = v0; v < vend; ++v) {
            int bb = batch[v];
            if (bb != prev) { atomicAdd(&cnt[prev], c0); prev = bb; c0 = 0; }
            ++c0;
        }
        atomicAdd(&cnt[prev], c0);
    }
}

// ---------- final linear + layernorm, one block per graph ----------
__global__ __launch_bounds__(256) void k_out(const float* __restrict__ pool,
                                             const int* __restrict__ cnt,
                                             const float* __restrict__ Wout,
                                             const float* __restrict__ bout,
                                             const float* __restrict__ gamma,
                                             const float* __restrict__ beta,
                                             float* __restrict__ out) {
    __shared__ float ps[HD];
    __shared__ float red[DM];
    int g = blockIdx.x, t = threadIdx.x;
    if (t < HD) {
        float cn = fmaxf((float)cnt[g], 1.0f);
        ps[t] = pool[g * HD + t] / cn;
    }
    __syncthreads();
    float acc = bout[t];
    #pragma unroll 8
    for (int k = 0; k < HD; ++k) acc = fmaf(ps[k], Wout[k * DM + t], acc);
    red[t] = acc; __syncthreads();
    for (int s2 = 128; s2 > 0; s2 >>= 1) {
        if (t < s2) red[t] += red[t + s2];
        __syncthreads();
    }
    float mu = red[0] * (1.0f / DM);
    __syncthreads();
    float d = acc - mu;
    red[t] = d * d; __syncthreads();
    for (int s2 = 128; s2 > 0; s2 >>= 1) {
        if (t < s2) red[t] += red[t + s2];
        __syncthreads();
    }
    float var = red[0] * (1.0f / DM);
    out[g * DM + t] = d * rsqrtf(var + EPSLN) * gamma[t] + beta[t];
}

extern "C" void kernel_launch(void* const* d_in, const int* in_sizes, int n_in,
                              void* d_out, int out_size, void* d_ws, size_t ws_size,
                              hipStream_t stream) {
    const float* verts = (const float*)d_in[0];
    const int*   ei    = (const int*)d_in[1];
    const int*   batch = (const int*)d_in[2];
    const float* Win   = (const float*)d_in[3];
    const float* bin   = (const float*)d_in[4];
    const float* W1    = (const float*)d_in[5];
    const float* b1    = (const float*)d_in[6];
    const float* W2    = (const float*)d_in[7];
    const float* b2    = (const float*)d_in[8];
    const float* W3    = (const float*)d_in[9];
    const float* b3    = (const float*)d_in[10];
    const float* Wout  = (const float*)d_in[11];
    const float* bout  = (const float*)d_in[12];
    const float* gamma = (const float*)d_in[13];
    const float* beta  = (const float*)d_in[14];
    float* out = (float*)d_out;

    char* wp = (char*)d_ws;
    auto alloc = [&](size_t bytes) -> char* {
        char* p = wp;
        wp += (bytes + 255) & ~(size_t)255;
        return p;
    };
    unsigned short* bufA = (unsigned short*)alloc((size_t)NV * HD * 2);
    unsigned short* bufB = (unsigned short*)alloc((size_t)NV * HD * 2);
    unsigned short* Wt   = (unsigned short*)alloc((size_t)2 * HD * HD * 2);
    int*   degi     = (int*)alloc((size_t)NV * 4);
    float* dinv     = (float*)alloc((size_t)NV * 4);
    int*   rowstart = (int*)alloc((size_t)NV * 4);
    int*   csr      = (int*)alloc((size_t)NBUCK * BCAP * 4);
    int*   ebuf     = (int*)alloc((size_t)NBUCK * BCAP * 4);
    // contiguous zero region: bcursor | pool | cnt -> one memset
    char*  zblock   = alloc(1024 + (size_t)NB * HD * 4 + 1024);
    int*   bcursor  = (int*)zblock;
    float* pool     = (float*)(zblock + 1024);
    int*   cnt      = (int*)(zblock + 1024 + (size_t)NB * HD * 4);

    hipMemsetAsync(zblock, 0, 1024 + (size_t)NB * HD * 4 + 1024, stream);

    // fused init: edge scatter + layer-1 H + W transpose
    k_init<<<NEB2 + H1B + WTB, 256, 0, stream>>>(verts, Win, bin, W1, W2, W3,
                                                 ei, bcursor, ebuf, bufA, Wt);
    // per-bucket CSR build (LDS-staged)
    k_bcsr<<<NBUCK, 512, 0, stream>>>(ebuf, bcursor, degi, dinv, rowstart, csr);

    int aggrid = (int)(((size_t)NV * 64 + 255) / 256);
    // layer 1
    k_agg<<<aggrid, 256, 0, stream>>>(bufA, dinv, rowstart, degi, csr, b1, bufB);
    k_gemm_mfma<<<(NV + 63) / 64, 256, 0, stream>>>(bufB, Wt, bufA);
    // layer 2
    k_agg<<<aggrid, 256, 0, stream>>>(bufA, dinv, rowstart, degi, csr, b2, bufB);
    k_gemm_mfma<<<(NV + 63) / 64, 256, 0, stream>>>(bufB, Wt + (size_t)HD * HD, bufA);
    // layer 3
    k_agg<<<aggrid, 256, 0, stream>>>(bufA, dinv, rowstart, degi, csr, b3, bufB);

    k_pool<<<2048, 256, 0, stream>>>(bufB, batch, pool, cnt);
    k_out<<<NB, 256, 0, stream>>>(pool, cnt, Wout, bout, gamma, beta, out);
}